// Round 3
// baseline (149.065 us; speedup 1.0000x reference)
//
#include <hip/hip_runtime.h>
#include <hip/hip_bf16.h>

#define NN 16384
#define DD 512
#define CC 256

typedef short bf16x8 __attribute__((ext_vector_type(8)));
typedef short bf16x4 __attribute__((ext_vector_type(4)));
typedef float f32x4 __attribute__((ext_vector_type(4)));

__device__ __forceinline__ short f2bf(float x) {
  __hip_bfloat16 h = __float2bfloat16(x);
  return __builtin_bit_cast(short, h);
}

__global__ void k_zero(float* __restrict__ p, int n, float* __restrict__ out) {
  int i = blockIdx.x * blockDim.x + threadIdx.x;
  if (i < n) p[i] = 0.f;
  if (i == 0) *out = 0.f;
}

// grid = 2 tensors * 256 classes * 2 chunks = 1024 blocks, 256 threads
__global__ void k_scatter(const float* __restrict__ src, const float* __restrict__ trg,
                          const int* __restrict__ lab_s, const int* __restrict__ lab_t,
                          float* __restrict__ sum_s, float* __restrict__ sum_t,
                          float* __restrict__ cnt_s, float* __restrict__ cnt_t) {
  const int b = blockIdx.x;
  const int t = b >> 9;           // tensor 0/1
  const int c = (b >> 1) & 255;   // class
  const int chunk = b & 1;        // row chunk of 8192
  const float* feat = t ? trg : src;
  const int* lab = t ? lab_t : lab_s;
  float* sum = t ? sum_t : sum_s;
  float* cnt = t ? cnt_t : cnt_s;
  const int tid = threadIdx.x;
  const int lane = tid & 63;
  const int row0 = chunk * 8192;

  float a0 = 0.f, a1 = 0.f;
  int count = 0;
  for (int it = 0; it < 128; ++it) {
    const int rbase = row0 + it * 64;
    const int l = lab[rbase + lane];
    unsigned long long m = __ballot(l == c);   // identical in all 4 waves
    count += (int)__popcll(m);
    while (m) {
      const int bit = __builtin_ctzll(m);
      m &= m - 1;
      const float* rp = feat + (size_t)(rbase + bit) * DD;
      a0 += rp[tid];
      a1 += rp[tid + 256];
    }
  }
  atomicAdd(sum + c * DD + tid, a0);
  atomicAdd(sum + c * DD + tid + 256, a1);
  if (tid == 0) atomicAdd(cnt + c, (float)count);
}

// grid = 256 (class), 256 threads.
// Writes the 3 prototype matrices in PACKED MFMA B-fragment order:
// per mat (131072 u16): elem = kc*8192 + tile*512 + (lhi*16+llo)*8 + j
//   where kc=k>>5, lhi=(k>>3)&3, j=k&7, tile=c>>4, llo=c&15.
__global__ void k_u(const float* __restrict__ sum_s, const float* __restrict__ sum_t,
                    const float* __restrict__ cnt_s, const float* __restrict__ cnt_t,
                    unsigned short* __restrict__ Upk) {
  const int c = blockIdx.x, tid = threadIdx.x;
  const float cs = cnt_s[c], ct = cnt_t[c];
  const float rs = 1.f / cs, rt = 1.f / ct, rst = 1.f / (cs + ct);
  const int tile = c >> 4, llo = c & 15;
#pragma unroll
  for (int kk = 0; kk < 2; ++kk) {
    const int k = tid + kk * 256;
    const float ss = sum_s[c * DD + k], st = sum_t[c * DD + k];
    const int kc = k >> 5, lhi = (k >> 3) & 3, j = k & 7;
    const int e = kc * 8192 + tile * 512 + (lhi * 16 + llo) * 8 + j;
    Upk[0 * 131072 + e] = (unsigned short)f2bf(ss * rs);
    Upk[1 * 131072 + e] = (unsigned short)f2bf(st * rt);
    Upk[2 * 131072 + e] = (unsigned short)f2bf((ss + st) * rst);
  }
}

// grid = 256 blocks, 1024 threads (16 waves: wr=w>>2 row-group, cw=w&3 col-group).
// Block owns 128 rows x 768 cols (3 mats x 256). A (cvt'd fp32->bf16) and B
// (pre-packed Upk) both double-buffered in LDS; one barrier per K-chunk.
__global__ __launch_bounds__(1024) void k_main(
    const float* __restrict__ src, const float* __restrict__ trg,
    const unsigned short* __restrict__ Upk, float* __restrict__ out) {
  __shared__ short Bs[2][24576];   // 2 x 48 KB, 48 units of 1KB per buf
  __shared__ short As[2][5120];    // 2 x 10 KB: 128 rows, 80-byte pitch
  __shared__ float smax[3][4][128];
  __shared__ float ssum[3][4][128];
  __shared__ float bred[16];

  const int tid = threadIdx.x;
  const int w = tid >> 6, lane = tid & 63;
  const int lhi = lane >> 4, llo = lane & 15;
  const int wr = w >> 2, cw = w & 3;
  const int row0 = blockIdx.x * 128;
  const float* feat = (row0 < NN) ? src + (size_t)row0 * DD
                                  : trg + (size_t)(row0 - NN) * DD;

  // A staging role: thread -> (row, float4-within-32col-chunk)
  const int arow = tid >> 3;   // 0..127
  const int ac8 = tid & 7;     // 0..7
  const float* aptr = feat + (size_t)arow * DD + ac8 * 4;
  char* const awr0 = (char*)&As[0][0] + arow * 80 + ac8 * 8;
  char* const awr1 = (char*)&As[1][0] + arow * 80 + ac8 * 8;

  f32x4 acc[3][2][4];
#pragma unroll
  for (int m = 0; m < 3; ++m)
#pragma unroll
    for (int rt = 0; rt < 2; ++rt)
#pragma unroll
      for (int ct = 0; ct < 4; ++ct)
        acc[m][rt][ct] = (f32x4){0.f, 0.f, 0.f, 0.f};

  auto stageB = [&](int kc, int buf) {
#pragma unroll
    for (int s = 0; s < 3; ++s) {
      const int u = s * 16 + w;
      const unsigned short* g =
          Upk + (size_t)(u >> 4) * 131072 + kc * 8192 + (u & 15) * 512 + lane * 8;
      __builtin_amdgcn_global_load_lds(
          (const __attribute__((address_space(1))) unsigned int*)g,
          (__attribute__((address_space(3))) unsigned int*)&Bs[buf][u * 512], 16, 0, 0);
    }
  };
  auto writeA = [&](const float4& v, char* dst) {
    bf16x4 b;
    b[0] = f2bf(v.x); b[1] = f2bf(v.y); b[2] = f2bf(v.z); b[3] = f2bf(v.w);
    *reinterpret_cast<bf16x4*>(dst) = b;
  };
  auto compute = [&](int buf) {
    bf16x8 afr[2];
#pragma unroll
    for (int rt = 0; rt < 2; ++rt)
      afr[rt] = *reinterpret_cast<const bf16x8*>(
          (const char*)&As[buf][0] + (wr * 32 + rt * 16 + llo) * 80 + lhi * 16);
#pragma unroll
    for (int m = 0; m < 3; ++m)
#pragma unroll
      for (int ct = 0; ct < 4; ++ct) {
        const bf16x8 b = *reinterpret_cast<const bf16x8*>(
            &Bs[buf][(m * 16 + cw * 4 + ct) * 512 + lane * 8]);
#pragma unroll
        for (int rt = 0; rt < 2; ++rt)
          acc[m][rt][ct] =
              __builtin_amdgcn_mfma_f32_16x16x32_bf16(afr[rt], b, acc[m][rt][ct], 0, 0, 0);
      }
  };

  // prologue: chunk 0 into buf 0
  {
    const float4 a0 = *reinterpret_cast<const float4*>(aptr);
    stageB(0, 0);
    writeA(a0, awr0);
  }
  __syncthreads();

#pragma unroll 1
  for (int it = 0; it < 8; ++it) {
    {  // consume buf0 (kc=2it), prefetch kc=2it+1 -> buf1  (2it+1 <= 15 always)
      const int kc = 2 * it;
      const float4 an = *reinterpret_cast<const float4*>(aptr + (kc + 1) * 32);
      stageB(kc + 1, 1);
      compute(0);
      writeA(an, awr1);
      __syncthreads();
    }
    {  // consume buf1 (kc=2it+1), prefetch kc=2it+2 -> buf0
      const int kc = 2 * it + 1;
      float4 an;
      if (kc < 15) {
        an = *reinterpret_cast<const float4*>(aptr + (kc + 1) * 32);
        stageB(kc + 1, 0);
      }
      compute(1);
      if (kc < 15) writeA(an, awr0);
      __syncthreads();
    }
  }

  // ---- epilogue: per-row logsumexp over 768 cols (C/D: col=llo, row=4*lhi+q) ----
  float lse[3][2][4];

#pragma unroll
  for (int m = 0; m < 3; ++m)
#pragma unroll
    for (int rt = 0; rt < 2; ++rt)
#pragma unroll
      for (int q = 0; q < 4; ++q) {
        float v = fmaxf(fmaxf(acc[m][rt][0][q], acc[m][rt][1][q]),
                        fmaxf(acc[m][rt][2][q], acc[m][rt][3][q]));
#pragma unroll
        for (int off = 1; off < 16; off <<= 1)
          v = fmaxf(v, __shfl_xor(v, off));
        if (llo == 0) smax[m][cw][wr * 32 + rt * 16 + lhi * 4 + q] = v;
      }
  __syncthreads();
#pragma unroll
  for (int m = 0; m < 3; ++m)
#pragma unroll
    for (int rt = 0; rt < 2; ++rt)
#pragma unroll
      for (int q = 0; q < 4; ++q) {
        const int r = wr * 32 + rt * 16 + lhi * 4 + q;
        lse[m][rt][q] = fmaxf(fmaxf(smax[m][0][r], smax[m][1][r]),
                              fmaxf(smax[m][2][r], smax[m][3][r]));
      }
#pragma unroll
  for (int m = 0; m < 3; ++m)
#pragma unroll
    for (int rt = 0; rt < 2; ++rt)
#pragma unroll
      for (int q = 0; q < 4; ++q) {
        float s = 0.f;
#pragma unroll
        for (int ct = 0; ct < 4; ++ct)
          s += __expf(acc[m][rt][ct][q] - lse[m][rt][q]);
#pragma unroll
        for (int off = 1; off < 16; off <<= 1)
          s += __shfl_xor(s, off);
        if (llo == 0) ssum[m][cw][wr * 32 + rt * 16 + lhi * 4 + q] = s;
      }
  __syncthreads();
#pragma unroll
  for (int m = 0; m < 3; ++m)
#pragma unroll
    for (int rt = 0; rt < 2; ++rt)
#pragma unroll
      for (int q = 0; q < 4; ++q) {
        const int r = wr * 32 + rt * 16 + lhi * 4 + q;
        const float S = ssum[m][0][r] + ssum[m][1][r] + ssum[m][2][r] + ssum[m][3][r];
        lse[m][rt][q] += __logf(S);
      }

  // fused symmetric-KL: sum of e^a(2a-b-c) + e^b(2b-a-c) + e^c(2c-a-b)
  float ks = 0.f;
#pragma unroll
  for (int rt = 0; rt < 2; ++rt)
#pragma unroll
    for (int ct = 0; ct < 4; ++ct)
#pragma unroll
      for (int q = 0; q < 4; ++q) {
        const float a = acc[0][rt][ct][q] - lse[0][rt][q];
        const float b = acc[1][rt][ct][q] - lse[1][rt][q];
        const float c = acc[2][rt][ct][q] - lse[2][rt][q];
        ks += __expf(a) * (2.f * a - b - c) + __expf(b) * (2.f * b - a - c) +
              __expf(c) * (2.f * c - a - b);
      }
#pragma unroll
  for (int off = 1; off < 64; off <<= 1)
    ks += __shfl_xor(ks, off);
  if (lane == 0) bred[w] = ks;
  __syncthreads();
  if (tid == 0) {
    float s = 0.f;
#pragma unroll
    for (int i = 0; i < 16; ++i) s += bred[i];
    atomicAdd(out, s * (1.f / 50331648.f));  // 1/(6 * 2N * C)
  }
}

extern "C" void kernel_launch(void* const* d_in, const int* in_sizes, int n_in,
                              void* d_out, int out_size, void* d_ws, size_t ws_size,
                              hipStream_t stream) {
  const float* src = (const float*)d_in[0];
  const float* trg = (const float*)d_in[1];
  const int* lab_s = (const int*)d_in[2];
  const int* lab_t = (const int*)d_in[3];
  float* out = (float*)d_out;

  float* sum_s = (float*)d_ws;            // [256*512]
  float* sum_t = sum_s + CC * DD;         // [256*512]
  float* cnt_s = sum_t + CC * DD;         // [256]
  float* cnt_t = cnt_s + CC;              // [256]
  unsigned short* Upk = (unsigned short*)(cnt_t + CC);  // 3 x [131072] packed bf16

  const int nz = 2 * CC * DD + 2 * CC;
  k_zero<<<(nz + 255) / 256, 256, 0, stream>>>(sum_s, nz, out);
  k_scatter<<<1024, 256, 0, stream>>>(src, trg, lab_s, lab_t, sum_s, sum_t, cnt_s, cnt_t);
  k_u<<<CC, 256, 0, stream>>>(sum_s, sum_t, cnt_s, cnt_t, Upk);
  k_main<<<256, 1024, 0, stream>>>(src, trg, Upk, out);
}

// Round 4
// 93.721 us; speedup vs baseline: 1.5905x; 1.5905x over previous
//
#include <hip/hip_runtime.h>
#include <hip/hip_bf16.h>

#define NN 16384
#define DD 512
#define CC 256
#define CAP 192

typedef short bf16x8 __attribute__((ext_vector_type(8)));
typedef short bf16x4 __attribute__((ext_vector_type(4)));
typedef float f32x4 __attribute__((ext_vector_type(4)));

__device__ __forceinline__ short f2bf(float x) {
  __hip_bfloat16 h = __float2bfloat16(x);
  return __builtin_bit_cast(short, h);
}

__global__ void k_zero(int* __restrict__ cur, float* __restrict__ out) {
  cur[threadIdx.x] = 0;
  if (threadIdx.x == 0) *out = 0.f;
}

// 32768 rows -> per-(tensor,class) index lists. grid 128 x 256.
__global__ void k_bucket(const int* __restrict__ lab_s, const int* __restrict__ lab_t,
                         int* __restrict__ cur, int* __restrict__ idx) {
  const int i = blockIdx.x * 256 + threadIdx.x;
  const int t = i >> 14, r = i & 16383;
  const int c = (t ? lab_t : lab_s)[r];
  const int tc = t * 256 + c;
  const int pos = atomicAdd(&cur[tc], 1);
  if (pos < CAP) idx[tc * CAP + pos] = r;
}

// grid 512 (one block per (tensor,class)), 256 threads. No atomics.
__global__ void k_gather(const float* __restrict__ src, const float* __restrict__ trg,
                         const int* __restrict__ cur, const int* __restrict__ idx,
                         float* __restrict__ sum_s, float* __restrict__ sum_t,
                         float* __restrict__ cnt_s, float* __restrict__ cnt_t) {
  const int tc = blockIdx.x;
  const int t = tc >> 8, c = tc & 255;
  const float* feat = t ? trg : src;
  float* sum = t ? sum_t : sum_s;
  float* cnt = t ? cnt_t : cnt_s;
  const int tid = threadIdx.x;
  const int count = min(cur[tc], CAP);

  __shared__ int lidx[CAP];
  if (tid < count) lidx[tid] = idx[tc * CAP + tid];
  __syncthreads();

  float a0 = 0.f, a1 = 0.f, b0 = 0.f, b1 = 0.f;
  int r = 0;
  for (; r + 2 <= count; r += 2) {
    const float* p0 = feat + (size_t)lidx[r] * DD;
    const float* p1 = feat + (size_t)lidx[r + 1] * DD;
    a0 += p0[tid]; a1 += p0[tid + 256];
    b0 += p1[tid]; b1 += p1[tid + 256];
  }
  if (r < count) {
    const float* p0 = feat + (size_t)lidx[r] * DD;
    a0 += p0[tid]; a1 += p0[tid + 256];
  }
  sum[c * DD + tid] = a0 + b0;
  sum[c * DD + tid + 256] = a1 + b1;
  if (tid == 0) cnt[c] = (float)count;
}

// grid = 256 (class), 256 threads.
// Writes the 3 prototype matrices in PACKED MFMA B-fragment order:
// per mat (131072 u16): elem = kc*8192 + tile*512 + (lhi*16+llo)*8 + j
//   where kc=k>>5, lhi=(k>>3)&3, j=k&7, tile=c>>4, llo=c&15.
__global__ void k_u(const float* __restrict__ sum_s, const float* __restrict__ sum_t,
                    const float* __restrict__ cnt_s, const float* __restrict__ cnt_t,
                    unsigned short* __restrict__ Upk) {
  const int c = blockIdx.x, tid = threadIdx.x;
  const float cs = cnt_s[c], ct = cnt_t[c];
  const float rs = 1.f / cs, rt = 1.f / ct, rst = 1.f / (cs + ct);
  const int tile = c >> 4, llo = c & 15;
#pragma unroll
  for (int kk = 0; kk < 2; ++kk) {
    const int k = tid + kk * 256;
    const float ss = sum_s[c * DD + k], st = sum_t[c * DD + k];
    const int kc = k >> 5, lhi = (k >> 3) & 3, j = k & 7;
    const int e = kc * 8192 + tile * 512 + (lhi * 16 + llo) * 8 + j;
    Upk[0 * 131072 + e] = (unsigned short)f2bf(ss * rs);
    Upk[1 * 131072 + e] = (unsigned short)f2bf(st * rt);
    Upk[2 * 131072 + e] = (unsigned short)f2bf((ss + st) * rst);
  }
}

// grid = 512 blocks, 1024 threads (16 waves: wr=w>>2 row-group of 16 rows,
// cw=w&3 col-group of 64 cols per mat). Block: 64 rows x 768 cols.
// acc = 3 mats x 4 ct x f32x4 = 48 VGPR. __launch_bounds__(1024,4) -> 128 VGPR budget.
__global__ __launch_bounds__(1024, 4) void k_main(
    const float* __restrict__ src, const float* __restrict__ trg,
    const unsigned short* __restrict__ Upk, float* __restrict__ out) {
  __shared__ short Bs[2][24576];   // 2 x 48 KB, 48 units of 1KB per buf
  __shared__ short As[2][2560];    // 2 x 5 KB: 64 rows, 80-byte pitch
  __shared__ float smax[3][4][64];
  __shared__ float ssum[3][4][64];
  __shared__ float bred[16];

  const int tid = threadIdx.x;
  const int w = tid >> 6, lane = tid & 63;
  const int lhi = lane >> 4, llo = lane & 15;
  const int wr = w >> 2, cw = w & 3;
  const int row0 = blockIdx.x * 64;
  const float* feat = (row0 < NN) ? src + (size_t)row0 * DD
                                  : trg + (size_t)(row0 - NN) * DD;

  // A staging role (tid < 512): thread -> (row 0..63, float4 0..7)
  const bool am = tid < 512;
  const int arow = tid >> 3, ac8 = tid & 7;
  const float* aptr = feat + (size_t)arow * DD + ac8 * 4;
  char* const awr0 = (char*)&As[0][0] + arow * 80 + ac8 * 8;
  char* const awr1 = (char*)&As[1][0] + arow * 80 + ac8 * 8;

  f32x4 acc[3][4];
#pragma unroll
  for (int m = 0; m < 3; ++m)
#pragma unroll
    for (int ct = 0; ct < 4; ++ct)
      acc[m][ct] = (f32x4){0.f, 0.f, 0.f, 0.f};

  auto stageB = [&](int kc, int buf) {
#pragma unroll
    for (int s = 0; s < 3; ++s) {
      const int u = s * 16 + w;
      const unsigned short* g =
          Upk + (size_t)(u >> 4) * 131072 + kc * 8192 + (u & 15) * 512 + lane * 8;
      __builtin_amdgcn_global_load_lds(
          (const __attribute__((address_space(1))) unsigned int*)g,
          (__attribute__((address_space(3))) unsigned int*)&Bs[buf][u * 512], 16, 0, 0);
    }
  };
  auto writeA = [&](const float4& v, char* dst) {
    bf16x4 b;
    b[0] = f2bf(v.x); b[1] = f2bf(v.y); b[2] = f2bf(v.z); b[3] = f2bf(v.w);
    *reinterpret_cast<bf16x4*>(dst) = b;
  };
  auto compute = [&](int buf) {
    const bf16x8 afr = *reinterpret_cast<const bf16x8*>(
        (const char*)&As[buf][0] + (wr * 16 + llo) * 80 + lhi * 16);
#pragma unroll
    for (int m = 0; m < 3; ++m)
#pragma unroll
      for (int ct = 0; ct < 4; ++ct) {
        const bf16x8 b = *reinterpret_cast<const bf16x8*>(
            &Bs[buf][(m * 16 + cw * 4 + ct) * 512 + lane * 8]);
        acc[m][ct] =
            __builtin_amdgcn_mfma_f32_16x16x32_bf16(afr, b, acc[m][ct], 0, 0, 0);
      }
  };

  // prologue: chunk 0 into buf 0
  {
    float4 a0;
    if (am) a0 = *reinterpret_cast<const float4*>(aptr);
    stageB(0, 0);
    if (am) writeA(a0, awr0);
  }
  __syncthreads();

#pragma unroll 1
  for (int it = 0; it < 8; ++it) {
    {  // consume buf0 (kc=2it), prefetch kc+1 -> buf1 (2it+1 <= 15 always)
      const int kc = 2 * it;
      float4 an;
      if (am) an = *reinterpret_cast<const float4*>(aptr + (kc + 1) * 32);
      stageB(kc + 1, 1);
      compute(0);
      if (am) writeA(an, awr1);
      __syncthreads();
    }
    {  // consume buf1 (kc=2it+1), prefetch kc+2 -> buf0
      const int kc = 2 * it + 1;
      float4 an;
      if (kc < 15) {
        if (am) an = *reinterpret_cast<const float4*>(aptr + (kc + 1) * 32);
        stageB(kc + 1, 0);
      }
      compute(1);
      if (kc < 15 && am) writeA(an, awr0);
      __syncthreads();
    }
  }

  // ---- epilogue: per-row logsumexp over 768 cols (C/D: col=llo, row=4*lhi+q) ----
  float lse[3][4];  // [mat][q]

#pragma unroll
  for (int m = 0; m < 3; ++m)
#pragma unroll
    for (int q = 0; q < 4; ++q) {
      float v = fmaxf(fmaxf(acc[m][0][q], acc[m][1][q]),
                      fmaxf(acc[m][2][q], acc[m][3][q]));
#pragma unroll
      for (int off = 1; off < 16; off <<= 1)
        v = fmaxf(v, __shfl_xor(v, off));
      if (llo == 0) smax[m][cw][wr * 16 + lhi * 4 + q] = v;
    }
  __syncthreads();
#pragma unroll
  for (int m = 0; m < 3; ++m)
#pragma unroll
    for (int q = 0; q < 4; ++q) {
      const int r = wr * 16 + lhi * 4 + q;
      lse[m][q] = fmaxf(fmaxf(smax[m][0][r], smax[m][1][r]),
                        fmaxf(smax[m][2][r], smax[m][3][r]));
    }
#pragma unroll
  for (int m = 0; m < 3; ++m)
#pragma unroll
    for (int q = 0; q < 4; ++q) {
      float s = 0.f;
#pragma unroll
      for (int ct = 0; ct < 4; ++ct)
        s += __expf(acc[m][ct][q] - lse[m][q]);
#pragma unroll
      for (int off = 1; off < 16; off <<= 1)
        s += __shfl_xor(s, off);
      if (llo == 0) ssum[m][cw][wr * 16 + lhi * 4 + q] = s;
    }
  __syncthreads();
#pragma unroll
  for (int m = 0; m < 3; ++m)
#pragma unroll
    for (int q = 0; q < 4; ++q) {
      const int r = wr * 16 + lhi * 4 + q;
      const float S = ssum[m][0][r] + ssum[m][1][r] + ssum[m][2][r] + ssum[m][3][r];
      lse[m][q] += __logf(S);
    }

  // fused symmetric-KL: sum of e^a(2a-b-c) + e^b(2b-a-c) + e^c(2c-a-b)
  float ks = 0.f;
#pragma unroll
  for (int ct = 0; ct < 4; ++ct)
#pragma unroll
    for (int q = 0; q < 4; ++q) {
      const float a = acc[0][ct][q] - lse[0][q];
      const float b = acc[1][ct][q] - lse[1][q];
      const float c = acc[2][ct][q] - lse[2][q];
      ks += __expf(a) * (2.f * a - b - c) + __expf(b) * (2.f * b - a - c) +
            __expf(c) * (2.f * c - a - b);
    }
#pragma unroll
  for (int off = 1; off < 64; off <<= 1)
    ks += __shfl_xor(ks, off);
  if (lane == 0) bred[w] = ks;
  __syncthreads();
  if (tid == 0) {
    float s = 0.f;
#pragma unroll
    for (int i = 0; i < 16; ++i) s += bred[i];
    atomicAdd(out, s * (1.f / 50331648.f));  // 1/(6 * 2N * C)
  }
}

extern "C" void kernel_launch(void* const* d_in, const int* in_sizes, int n_in,
                              void* d_out, int out_size, void* d_ws, size_t ws_size,
                              hipStream_t stream) {
  const float* src = (const float*)d_in[0];
  const float* trg = (const float*)d_in[1];
  const int* lab_s = (const int*)d_in[2];
  const int* lab_t = (const int*)d_in[3];
  float* out = (float*)d_out;

  float* sum_s = (float*)d_ws;                  // [256*512]
  float* sum_t = sum_s + CC * DD;               // [256*512]
  float* cnt_s = sum_t + CC * DD;               // [256]
  float* cnt_t = cnt_s + CC;                    // [256]
  int* cur = (int*)(cnt_t + CC);                // [512]
  int* idx = cur + 512;                         // [512*CAP]
  unsigned short* Upk = (unsigned short*)(idx + 512 * CAP);  // 3 x [131072] bf16

  k_zero<<<1, 512, 0, stream>>>(cur, out);
  k_bucket<<<128, 256, 0, stream>>>(lab_s, lab_t, cur, idx);
  k_gather<<<512, 256, 0, stream>>>(src, trg, cur, idx, sum_s, sum_t, cnt_s, cnt_t);
  k_u<<<CC, 256, 0, stream>>>(sum_s, sum_t, cnt_s, cnt_t, Upk);
  k_main<<<512, 1024, 0, stream>>>(src, trg, Upk, out);
}